// Round 5
// baseline (439.776 us; speedup 1.0000x reference)
//
#include <hip/hip_runtime.h>

// LatentClassifier collapse (all f32 I/O):
//   All depth-loop layernorms act on singleton axes -> LN(x) == bias exactly.
//   => h = x + c[t]; out = (gelu((x+c) @ P^T + pooler_b)) @ cls_w^T + cls_b
//   c per-column => (x+c)@P^T = x@P^T + d[s], d[s] = sum_t c[t]*P[s,t]
// FP32 inputs, no fp32 MFMA -> convert x,P to bf16 once (ws), one 4096^3 bf16
// MFMA GEMM with fused gelu/cls epilogue atomicAdd into d_out.
//
// R3: XOR swizzle killed bank conflicts -> 1025 TF. R4: fatter tile was a wash
// (lost co-residency). R5: back to 128x128 / 2x2 waves, BK=32, LDS DOUBLE
// BUFFER with prefetch-issued-before-compute and ONE barrier per slab: the
// compiler's vmcnt(0)-before-s_barrier drain now lands after the MFMA block,
// so staging latency is hidden by compute. 32 KB LDS -> 4 blocks/CU.

#define K_DIM 4096

typedef __bf16 bf16x8 __attribute__((ext_vector_type(8)));
typedef float f32x4 __attribute__((ext_vector_type(4)));

__device__ __forceinline__ ushort f2bf(float f) {
    unsigned int u = __float_as_uint(f);
    u = (u + 0x7fffu + ((u >> 16) & 1u)) >> 16;  // RTNE
    return (ushort)u;
}

__device__ __forceinline__ float gelu_exact(float x) {
    return 0.5f * x * (1.0f + erff(x * 0.70710678118654752440f));
}

__device__ __forceinline__ void gld16(const void* g, void* l) {
    __builtin_amdgcn_global_load_lds(
        (__attribute__((address_space(1))) void*)(g),
        (__attribute__((address_space(3))) void*)(l), 16, 0, 0);
}

// ---------- K0: f32 -> bf16 convert of x and pooler_w in one launch -------------
__global__ __launch_bounds__(256) void cvt2_kernel(const float* __restrict__ s0,
                                                   ushort* __restrict__ d0,
                                                   const float* __restrict__ s1,
                                                   ushort* __restrict__ d1) {
    int b = blockIdx.x;
    const float* src = (b < 8192) ? s0 : s1;
    ushort* dst = (b < 8192) ? d0 : d1;
    int i = (b & 8191) * 256 + threadIdx.x;  // 8 floats each
    const float4* s4 = (const float4*)src + (size_t)i * 2;
    float4 a = s4[0], c = s4[1];
    union { ushort u[8]; uint4 v; } r;
    r.u[0] = f2bf(a.x); r.u[1] = f2bf(a.y); r.u[2] = f2bf(a.z); r.u[3] = f2bf(a.w);
    r.u[4] = f2bf(c.x); r.u[5] = f2bf(c.y); r.u[6] = f2bf(c.z); r.u[7] = f2bf(c.w);
    ((uint4*)dst)[i] = r.v;
}

// ---------- K1: R_i[t] = rowsum(sgu_proj_w[i,t,:]); 0 fast-path when beta==0 ----
__global__ __launch_bounds__(256) void rowsum_kernel(const float* __restrict__ proj_w,
                                                     const float* __restrict__ sgu_ln_b,
                                                     float* __restrict__ R) {
    int wid  = (blockIdx.x * 256 + threadIdx.x) >> 6;  // 0..8191 (= layer*4096 + t)
    int lane = threadIdx.x & 63;
    int layer = wid >> 12;
    float beta = sgu_ln_b[layer];
    if (beta == 0.0f) {  // wave-uniform; inputs identical every call
        if (lane == 0) R[wid] = 0.0f;
        return;
    }
    const float* pr = proj_w + (size_t)wid * K_DIM;
    float s = 0.0f;
    for (int it = 0; it < 16; ++it) {
        float4 pv = *(const float4*)&pr[it * 256 + lane * 4];
        s += pv.x + pv.y + pv.z + pv.w;
    }
#pragma unroll
    for (int m = 1; m < 64; m <<= 1) s += __shfl_xor(s, m);
    if (lane == 0) R[wid] = s;
}

// ---------- K2: c[t]; also init d_out[t] = cls_b --------------------------------
__global__ __launch_bounds__(256) void c_kernel(const float* __restrict__ ln1_b,
                                                const float* __restrict__ cp1_w,
                                                const float* __restrict__ cp1_b,
                                                const float* __restrict__ sgu_ln_b,
                                                const float* __restrict__ sgu_proj_b,
                                                const float* __restrict__ cp2_w,
                                                const float* __restrict__ cp2_b,
                                                const float* __restrict__ cls_b,
                                                const float* __restrict__ R,
                                                float* __restrict__ c,
                                                float* __restrict__ out) {
    int t = blockIdx.x * 256 + threadIdx.x;  // 0..4095
    float cv = 0.0f;
#pragma unroll
    for (int i = 0; i < 2; ++i) {
        float alpha = gelu_exact(ln1_b[i] * cp1_w[i * 2 + 0] + cp1_b[i * 2 + 0]);
        float beta  = sgu_ln_b[i];
        float v     = beta * R[i * 4096 + t] + sgu_proj_b[i * 4096 + t];
        cv += alpha * v * cp2_w[i] + cp2_b[i];
    }
    c[t]   = cv;
    out[t] = cls_b[0];  // d_out poisoned before every call -> re-init here
}

// ---------- K3: e[s] = sum_t c[t]*Pb[s,t] + pooler_b[s]  (Pb = bf16 copy) -------
__global__ __launch_bounds__(256) void e_kernel(const ushort* __restrict__ Pb,
                                                const float* __restrict__ c,
                                                const float* __restrict__ pooler_b,
                                                float* __restrict__ e) {
    int row  = blockIdx.x * 4 + (threadIdx.x >> 6);
    int lane = threadIdx.x & 63;
    const ushort* pr = Pb + (size_t)row * K_DIM;
    float s = 0.0f;
    for (int it = 0; it < 8; ++it) {
        int col = it * 512 + lane * 8;
        bf16x8 pv = *(const bf16x8*)&pr[col];
#pragma unroll
        for (int j = 0; j < 8; ++j) s += (float)pv[j] * c[col + j];
    }
#pragma unroll
    for (int m = 1; m < 64; m <<= 1) s += __shfl_xor(s, m);
    if (lane == 0) e[row] = s + pooler_b[row];
}

// ---------- K4: Y = x @ P^T (bf16 MFMA); fused gelu(Y+e)*cls_w row-reduce -------
// 128x128 block, BK=32, 4 waves (2x2, 64x64 each), LDS double-buffered.
// LDS layout per buffer (8 KB, rows of 64 B = 4 chunks of 16 B):
//   byte(row, chunk) = row*64 + (chunk ^ ((row>>1)&3))*16
// (swizzle on the GLOBAL chunk at staging since global_load_lds dst = t*16).
// Reader phase (16 lanes, fixed g): granule = (lo&1)*4 + (g^((lo>>1)&3))
// covers all 8 16B-granules -> 2-way bank access (free).
// Per slab: issue prefetch (slab+1 -> buf^1), compute from buf, ONE barrier.
__global__ __launch_bounds__(256, 2) void gemm_kernel(const ushort* __restrict__ X,
                                                      const ushort* __restrict__ P,
                                                      const float* __restrict__ clsW,
                                                      const float* __restrict__ e,
                                                      float* __restrict__ accOut) {
    __shared__ __align__(16) ushort As[2][128 * 32];  // 2 x 8 KB
    __shared__ __align__(16) ushort Bs[2][128 * 32];  // 2 x 8 KB

    const int t = threadIdx.x;
    const int bCol = blockIdx.x, bRow = blockIdx.y;
    const int lane = t & 63, wv = t >> 6;
    const int g = lane >> 4, lo = lane & 15;
    const int wm = wv >> 1, wn = wv & 1;

    f32x4 zero4 = {0.f, 0.f, 0.f, 0.f};
    f32x4 acc[4][4];
#pragma unroll
    for (int mi = 0; mi < 4; ++mi)
#pragma unroll
        for (int ni = 0; ni < 4; ++ni) acc[mi][ni] = zero4;

    // staging: 256 threads x 16B = 4 KB = 64 rows/round; A rows rl & rl+64.
    const int rl = t >> 2;                       // 0..63 local row
    const int cs = (t & 3) ^ ((rl >> 1) & 3);    // swizzled global 16B-chunk
    const ushort* gA = X + (size_t)(bRow * 128 + rl) * K_DIM + cs * 8;
    const ushort* gB = P + (size_t)(bCol * 128 + rl) * K_DIM + cs * 8;
    char* lA = (char*)As + t * 16;   // +4096 for rows 64..127; +8192 for buf 1
    char* lB = (char*)Bs + t * 16;

    // fragment read offsets (within one 8 KB buffer)
    const int ch = (g ^ ((lo >> 1) & 3)) * 16;   // swizzled chunk byte offset

    // prologue: stage slab 0 into buffer 0
    gld16(gA,              lA);
    gld16(gA + 64 * K_DIM, lA + 4096);
    gld16(gB,              lB);
    gld16(gB + 64 * K_DIM, lB + 4096);
    __syncthreads();

    int buf = 0;
    for (int k0 = 0; k0 < K_DIM; k0 += 32) {
        // issue prefetch of next slab into the other buffer (no wait here)
        if (k0 + 32 < K_DIM) {
            int nb = buf ^ 1;
            gld16(gA + (k0 + 32),              lA + nb * 8192);
            gld16(gA + (k0 + 32) + 64 * K_DIM, lA + nb * 8192 + 4096);
            gld16(gB + (k0 + 32),              lB + nb * 8192);
            gld16(gB + (k0 + 32) + 64 * K_DIM, lB + nb * 8192 + 4096);
        }

        // compute slab k0 from current buffer (ds_read waits lgkm only)
        bf16x8 af[4], bfr[4];
#pragma unroll
        for (int mi = 0; mi < 4; ++mi) {
            int row = wm * 64 + mi * 16 + lo;
            af[mi] = *(const bf16x8*)((const char*)As[buf] + row * 64 + ch);
        }
#pragma unroll
        for (int ni = 0; ni < 4; ++ni) {
            int col = wn * 64 + ni * 16 + lo;
            bfr[ni] = *(const bf16x8*)((const char*)Bs[buf] + col * 64 + ch);
        }
#pragma unroll
        for (int mi = 0; mi < 4; ++mi)
#pragma unroll
            for (int ni = 0; ni < 4; ++ni)
                acc[mi][ni] = __builtin_amdgcn_mfma_f32_16x16x32_bf16(af[mi], bfr[ni], acc[mi][ni], 0, 0, 0);

        // single barrier: vmcnt(0) drain of the prefetch lands AFTER the MFMAs,
        // so the loads had the whole compute phase to complete.
        __syncthreads();
        buf ^= 1;
    }

    // Epilogue: C/D layout col=lane&15, row=(lane>>4)*4+reg (m89-verified).
    int sColBase = bCol * 128 + wn * 64 + lo;
    float eb[4], cw[4];
#pragma unroll
    for (int ni = 0; ni < 4; ++ni) {
        int s = sColBase + ni * 16;
        eb[ni] = e[s];
        cw[ni] = clsW[s];
    }
#pragma unroll
    for (int mi = 0; mi < 4; ++mi) {
        int rowBase = bRow * 128 + wm * 64 + mi * 16 + g * 4;
#pragma unroll
        for (int r = 0; r < 4; ++r) {
            float sum = 0.0f;
#pragma unroll
            for (int ni = 0; ni < 4; ++ni) {
                float y = acc[mi][ni][r] + eb[ni];
                sum += gelu_exact(y) * cw[ni];
            }
            sum += __shfl_xor(sum, 1);
            sum += __shfl_xor(sum, 2);
            sum += __shfl_xor(sum, 4);
            sum += __shfl_xor(sum, 8);
            if (lo == 0) atomicAdd(&accOut[rowBase + r], sum);
        }
    }
}

extern "C" void kernel_launch(void* const* d_in, const int* in_sizes, int n_in,
                              void* d_out, int out_size, void* d_ws, size_t ws_size,
                              hipStream_t stream) {
    const float* x          = (const float*)d_in[0];
    const float* ln1_b      = (const float*)d_in[2];
    const float* cp1_w      = (const float*)d_in[3];
    const float* cp1_b      = (const float*)d_in[4];
    const float* sgu_ln_b   = (const float*)d_in[6];
    const float* sgu_proj_w = (const float*)d_in[7];
    const float* sgu_proj_b = (const float*)d_in[8];
    const float* cp2_w      = (const float*)d_in[9];
    const float* cp2_b      = (const float*)d_in[10];
    const float* pooler_w   = (const float*)d_in[11];
    const float* pooler_b   = (const float*)d_in[12];
    const float* cls_w      = (const float*)d_in[13];
    const float* cls_b      = (const float*)d_in[14];

    // ws layout: xb (32MB bf16) | pb (32MB bf16) | c(16KB) | e(16KB) | R(32KB)
    ushort* xb = (ushort*)d_ws;                  // 4096*4096 bf16
    ushort* pb = xb + (size_t)K_DIM * K_DIM;     // 4096*4096 bf16
    float*  fs = (float*)(pb + (size_t)K_DIM * K_DIM);
    float* c_buf = fs;
    float* e_buf = fs + 4096;
    float* R     = fs + 8192;
    float* out   = (float*)d_out;

    cvt2_kernel<<<16384, 256, 0, stream>>>(x, xb, pooler_w, pb);
    rowsum_kernel<<<2048, 256, 0, stream>>>(sgu_proj_w, sgu_ln_b, R);
    c_kernel<<<16, 256, 0, stream>>>(ln1_b, cp1_w, cp1_b, sgu_ln_b, sgu_proj_b,
                                     cp2_w, cp2_b, cls_b, R, c_buf, out);
    e_kernel<<<1024, 256, 0, stream>>>(pb, c_buf, pooler_b, e_buf);
    gemm_kernel<<<dim3(32, 32), 256, 0, stream>>>(xb, pb, cls_w, e_buf, out);
}